// Round 2
// baseline (401.348 us; speedup 1.0000x reference)
//
#include <hip/hip_runtime.h>

typedef float f32x4 __attribute__((ext_vector_type(4)));
typedef short bf16x8 __attribute__((ext_vector_type(8)));

#define DEV __device__ __forceinline__

constexpr int B_ = 8, H_ = 8, N_ = 784, D_ = 96, C_ = 768, NP_ = 800;
constexpr int NT = 49;                               // 16-wide tiles across N (49*16=784 exact)
constexpr float SCALE_ = 0.10206207261596575f;       // 96^-0.5
constexpr float INV_N = 1.0f / 784.0f;

// ---- workspace layout (bytes) ----
constexpr size_t SZ_QKH  = (size_t)B_*H_*N_*D_*2;    // 9,633,792
constexpr size_t OFF_QH  = 0;
constexpr size_t OFF_KH  = OFF_QH + SZ_QKH;
constexpr size_t OFF_VHT = OFF_KH + SZ_QKH;          // vh transposed (B,H,D,NP) bf16
constexpr size_t SZ_VHT  = (size_t)B_*H_*D_*NP_*2;   // 9,830,400
constexpr size_t OFF_Z   = OFF_VHT + SZ_VHT;         // (B,H,N) f32 softmax denominators
constexpr size_t SZ_Z    = (size_t)B_*H_*N_*4;
constexpr size_t OFF_G   = OFF_Z + SZ_Z;             // 36 pairs x 8 banks f32
constexpr size_t SZ_G    = 36*8*4;
constexpr size_t OFF_COEF= OFF_G + 2048;             // W'[64] + c[8] f32
constexpr size_t OFF_X   = OFF_COEF + 2048;          // (B,N,C) bf16
constexpr size_t SZ_X    = (size_t)B_*N_*C_*2;
constexpr size_t OFF_WPB = OFF_X + SZ_X;             // Wp bf16 (C,C)

DEV unsigned short f2bf(float f) {                   // RNE fp32 -> bf16
  unsigned u = __float_as_uint(f);
  u += 0x7FFFu + ((u >> 16) & 1u);
  return (unsigned short)(u >> 16);
}

DEV f32x4 mfma16(bf16x8 a, bf16x8 b, f32x4 c) {
  return __builtin_amdgcn_mfma_f32_16x16x32_bf16(a, b, c, 0, 0, 0);
}

// ---------------- K1: 3x3 conv over (3,16,16) token patches -> head layouts ----------------
__global__ __launch_bounds__(256) void k_conv(
    const float* __restrict__ q, const float* __restrict__ k, const float* __restrict__ v,
    const float* __restrict__ Wq, const float* __restrict__ Wk, const float* __restrict__ Wv,
    unsigned short* __restrict__ qh, unsigned short* __restrict__ kh, unsigned short* __restrict__ vht)
{
  __shared__ float sm[3][18][18];
  const int t = blockIdx.y;
  const int bn = blockIdx.x;
  const int b = bn / N_, n = bn % N_;
  const float* src = (t == 0) ? q : (t == 1) ? k : v;
  const float* W   = (t == 0) ? Wq : (t == 1) ? Wk : Wv;
  const int tid = threadIdx.x;
  for (int i = tid; i < 3*18*18; i += 256) ((float*)sm)[i] = 0.0f;
  __syncthreads();
  for (int i = tid; i < 768; i += 256) {
    int ch = i >> 8, rr = (i >> 4) & 15, cc = i & 15;
    sm[ch][rr+1][cc+1] = src[(size_t)bn*768 + i];
  }
  __syncthreads();
  const int r = tid >> 4, c = tid & 15;
  #pragma unroll
  for (int oc = 0; oc < 3; ++oc) {
    float acc = 0.0f;
    #pragma unroll
    for (int ic = 0; ic < 3; ++ic)
      #pragma unroll
      for (int dr = 0; dr < 3; ++dr)
        #pragma unroll
        for (int dc = 0; dc < 3; ++dc)
          acc += sm[ic][r+dr][c+dc] * W[((oc*3+ic)*3+dr)*3+dc];
    const int cidx = oc*256 + tid;
    const int h = cidx / 96, d = cidx % 96;
    if (t == 0) {
      qh[((size_t)(b*8+h)*N_ + n)*96 + d] = f2bf(acc * SCALE_);   // fold softmax scale into q
    } else if (t == 1) {
      kh[((size_t)(b*8+h)*N_ + n)*96 + d] = f2bf(acc);
    } else {
      vht[((size_t)(b*8+h)*96 + d)*NP_ + n] = f2bf(acc);          // transposed for PV B-operand
    }
  }
}

// ---------------- K1b: cast Wp to bf16 ----------------
__global__ __launch_bounds__(256) void k_cast(const float* __restrict__ wp, unsigned short* __restrict__ wpb) {
  const int i = (blockIdx.x*256 + threadIdx.x)*4;
  #pragma unroll
  for (int j = 0; j < 4; ++j) wpb[i+j] = f2bf(wp[i+j]);
}

// ---------------- K2a: softmax denominators Z[b,h,n] ----------------
__global__ __launch_bounds__(256) void k_zsum(const unsigned short* __restrict__ qh,
    const unsigned short* __restrict__ kh, float* __restrict__ Zout)
{
  __shared__ float zp[4][8][16];
  const int rt = blockIdx.x, b = blockIdx.y;
  const int tid = threadIdx.x, w = tid >> 6, lane = tid & 63, g = lane >> 4, ci = lane & 15;
  #pragma unroll
  for (int h = 0; h < 8; ++h) {
    const unsigned short* qp = qh + ((size_t)(b*8+h)*N_ + rt*16 + ci)*96 + g*8;
    bf16x8 a0 = *(const bf16x8*)(qp);
    bf16x8 a1 = *(const bf16x8*)(qp + 32);
    bf16x8 a2 = *(const bf16x8*)(qp + 64);
    float s0 = 0, s1 = 0, s2 = 0, s3 = 0;
    for (int mt = w; mt < NT; mt += 4) {
      const unsigned short* kp = kh + ((size_t)(b*8+h)*N_ + mt*16 + ci)*96 + g*8;
      bf16x8 b0 = *(const bf16x8*)(kp);
      bf16x8 b1 = *(const bf16x8*)(kp + 32);
      bf16x8 b2 = *(const bf16x8*)(kp + 64);
      f32x4 acc = {0.f, 0.f, 0.f, 0.f};
      acc = mfma16(a0, b0, acc); acc = mfma16(a1, b1, acc); acc = mfma16(a2, b2, acc);
      s0 += __expf(acc.x); s1 += __expf(acc.y); s2 += __expf(acc.z); s3 += __expf(acc.w);
    }
    #pragma unroll
    for (int m = 1; m < 16; m <<= 1) {
      s0 += __shfl_xor(s0, m); s1 += __shfl_xor(s1, m);
      s2 += __shfl_xor(s2, m); s3 += __shfl_xor(s3, m);
    }
    if (ci == 0) {
      zp[w][h][g*4+0] = s0; zp[w][h][g*4+1] = s1;
      zp[w][h][g*4+2] = s2; zp[w][h][g*4+3] = s3;
    }
  }
  __syncthreads();
  if (tid < 128) {
    const int h = tid >> 4, row = tid & 15;
    Zout[(size_t)(b*8+h)*N_ + rt*16 + row] =
        zp[0][h][row] + zp[1][h][row] + zp[2][h][row] + zp[3][h][row];
  }
}

// ---------------- K2b: centered cross-head second moments G'[36] ----------------
__global__ __launch_bounds__(256) void k_gstat(const unsigned short* __restrict__ qh,
    const unsigned short* __restrict__ kh, const float* __restrict__ Z, float* __restrict__ G)
{
  __shared__ float gred[4][36];
  const int rt = blockIdx.x, b = blockIdx.y;
  const int tid = threadIdx.x, w = tid >> 6, lane = tid & 63, g = lane >> 4, ci = lane & 15;
  float rZ[8][4];
  #pragma unroll
  for (int h = 0; h < 8; ++h)
    #pragma unroll
    for (int r = 0; r < 4; ++r)
      rZ[h][r] = 1.0f / Z[(size_t)(b*8+h)*N_ + rt*16 + g*4 + r];
  float Gacc[36];
  #pragma unroll
  for (int i = 0; i < 36; ++i) Gacc[i] = 0.f;
  for (int mt = w; mt < NT; mt += 4) {
    float cen[8][4];
    #pragma unroll
    for (int h = 0; h < 8; ++h) {
      const unsigned short* qp = qh + ((size_t)(b*8+h)*N_ + rt*16 + ci)*96 + g*8;
      bf16x8 a0 = *(const bf16x8*)(qp);
      bf16x8 a1 = *(const bf16x8*)(qp + 32);
      bf16x8 a2 = *(const bf16x8*)(qp + 64);
      const unsigned short* kp = kh + ((size_t)(b*8+h)*N_ + mt*16 + ci)*96 + g*8;
      bf16x8 b0 = *(const bf16x8*)(kp);
      bf16x8 b1 = *(const bf16x8*)(kp + 32);
      bf16x8 b2 = *(const bf16x8*)(kp + 64);
      f32x4 acc = {0.f, 0.f, 0.f, 0.f};
      acc = mfma16(a0, b0, acc); acc = mfma16(a1, b1, acc); acc = mfma16(a2, b2, acc);
      cen[h][0] = __expf(acc.x)*rZ[h][0] - INV_N;
      cen[h][1] = __expf(acc.y)*rZ[h][1] - INV_N;
      cen[h][2] = __expf(acc.z)*rZ[h][2] - INV_N;
      cen[h][3] = __expf(acc.w)*rZ[h][3] - INV_N;
    }
    int idx = 0;
    #pragma unroll
    for (int h1 = 0; h1 < 8; ++h1)
      #pragma unroll
      for (int h2 = h1; h2 < 8; ++h2) {
        Gacc[idx] += cen[h1][0]*cen[h2][0] + cen[h1][1]*cen[h2][1]
                   + cen[h1][2]*cen[h2][2] + cen[h1][3]*cen[h2][3];
        ++idx;
      }
  }
  #pragma unroll
  for (int i = 0; i < 36; ++i) {
    float vv = Gacc[i];
    #pragma unroll
    for (int m = 32; m >= 1; m >>= 1) vv += __shfl_xor(vv, m);
    Gacc[i] = vv;
  }
  if (lane == 0) {
    #pragma unroll
    for (int i = 0; i < 36; ++i) gred[w][i] = Gacc[i];
  }
  __syncthreads();
  if (tid < 36) {
    float s = gred[0][tid] + gred[1][tid] + gred[2][tid] + gred[3][tid];
    atomicAdd(&G[tid*8 + (blockIdx.x & 7)], s);
  }
}

// ---------------- K3: finalize BN-folded mixing coefficients ----------------
__global__ __launch_bounds__(64) void k_coef(const float* __restrict__ G,
    const float* __restrict__ Wre, const float* __restrict__ bre,
    const float* __restrict__ gamma, const float* __restrict__ beta,
    float* __restrict__ coef)
{
  const int o = threadIdx.x;
  if (o >= 8) return;
  float Gs[36];
  for (int i = 0; i < 36; ++i) {
    float s = 0;
    for (int j = 0; j < 8; ++j) s += G[i*8+j];
    Gs[i] = s;
  }
  float vs = 0; int idx = 0;
  for (int h1 = 0; h1 < 8; ++h1)
    for (int h2 = h1; h2 < 8; ++h2) {
      float ww = Wre[o*8+h1] * Wre[o*8+h2] * ((h1 == h2) ? 1.0f : 2.0f);
      vs += ww * Gs[idx]; ++idx;
    }
  const float var = vs * (1.0f / ((float)B_ * (float)N_ * (float)N_));
  const float scale = gamma[o] * rsqrtf(var + 1e-5f);
  float rowsum = 0;
  for (int h = 0; h < 8; ++h) rowsum += Wre[o*8+h];
  for (int h = 0; h < 8; ++h) coef[o*8+h] = scale * Wre[o*8+h];
  // mean_o = rowsum/N + bre_o ; c_o = beta + scale*(bre - mean) => bre cancels
  coef[64+o] = beta[o] - scale * rowsum * INV_N;
  (void)bre;
}

// ---------------- K4: fused QK^T -> p -> cross-head mix(+BN) -> PV ----------------
__global__ __launch_bounds__(256) void k_attn(const unsigned short* __restrict__ qh,
    const unsigned short* __restrict__ kh, const unsigned short* __restrict__ vht,
    const float* __restrict__ Z, const float* __restrict__ coef, unsigned short* __restrict__ xout)
{
  __shared__ float plds[8][16][36];   // [h][row][m-in-chunk, padded]
  const int rt = blockIdx.x, b = blockIdx.y;
  const int tid = threadIdx.x, w = tid >> 6, lane = tid & 63, g = lane >> 4, ci = lane & 15;
  float rZ[2][4];
  #pragma unroll
  for (int hl = 0; hl < 2; ++hl) {
    const int h = w*2 + hl;
    #pragma unroll
    for (int r = 0; r < 4; ++r)
      rZ[hl][r] = 1.0f / Z[(size_t)(b*8+h)*N_ + rt*16 + g*4 + r];
  }
  float wo[2][8], co[2];
  #pragma unroll
  for (int ol = 0; ol < 2; ++ol) {
    const int o = w*2 + ol;
    #pragma unroll
    for (int h = 0; h < 8; ++h) wo[ol][h] = coef[o*8+h];
    co[ol] = coef[64+o];
  }
  f32x4 xq[2][6];
  #pragma unroll
  for (int ol = 0; ol < 2; ++ol)
    #pragma unroll
    for (int dt = 0; dt < 6; ++dt) xq[ol][dt] = (f32x4){0.f, 0.f, 0.f, 0.f};

  for (int mc = 0; mc < 25; ++mc) {
    const int m0 = mc*32;
    // phase 1: this wave computes p for heads 2w, 2w+1 over the 32-wide m-chunk
    #pragma unroll
    for (int hl = 0; hl < 2; ++hl) {
      const int h = w*2 + hl;
      const unsigned short* qp = qh + ((size_t)(b*8+h)*N_ + rt*16 + ci)*96 + g*8;
      bf16x8 a0 = *(const bf16x8*)(qp);
      bf16x8 a1 = *(const bf16x8*)(qp + 32);
      bf16x8 a2 = *(const bf16x8*)(qp + 64);
      #pragma unroll
      for (int hf = 0; hf < 2; ++hf) {
        const int mt0 = m0 + hf*16;
        float p0 = 0, p1 = 0, p2 = 0, p3 = 0;
        if (mt0 < N_) {
          const unsigned short* kp = kh + ((size_t)(b*8+h)*N_ + mt0 + ci)*96 + g*8;
          bf16x8 b0 = *(const bf16x8*)(kp);
          bf16x8 b1 = *(const bf16x8*)(kp + 32);
          bf16x8 b2 = *(const bf16x8*)(kp + 64);
          f32x4 acc = {0.f, 0.f, 0.f, 0.f};
          acc = mfma16(a0, b0, acc); acc = mfma16(a1, b1, acc); acc = mfma16(a2, b2, acc);
          p0 = __expf(acc.x)*rZ[hl][0]; p1 = __expf(acc.y)*rZ[hl][1];
          p2 = __expf(acc.z)*rZ[hl][2]; p3 = __expf(acc.w)*rZ[hl][3];
        }
        plds[h][g*4+0][hf*16+ci] = p0;
        plds[h][g*4+1][hf*16+ci] = p1;
        plds[h][g*4+2][hf*16+ci] = p2;
        plds[h][g*4+3][hf*16+ci] = p3;
      }
    }
    __syncthreads();
    // phase 2: read p in A-fragment layout, mix (BN folded), PV for heads 2w, 2w+1
    f32x4 pva[8], pvb[8];
    #pragma unroll
    for (int h = 0; h < 8; ++h) {
      const float* pp = &plds[h][ci][g*8];
      pva[h] = *(const f32x4*)(pp);
      pvb[h] = *(const f32x4*)(pp + 4);
    }
    #pragma unroll
    for (int ol = 0; ol < 2; ++ol) {
      float at0 = co[ol], at1 = co[ol], at2 = co[ol], at3 = co[ol];
      float at4 = co[ol], at5 = co[ol], at6 = co[ol], at7 = co[ol];
      #pragma unroll
      for (int h = 0; h < 8; ++h) {
        const float wv = wo[ol][h];
        at0 += wv*pva[h].x; at1 += wv*pva[h].y; at2 += wv*pva[h].z; at3 += wv*pva[h].w;
        at4 += wv*pvb[h].x; at5 += wv*pvb[h].y; at6 += wv*pvb[h].z; at7 += wv*pvb[h].w;
      }
      bf16x8 af;
      af[0] = (short)f2bf(at0); af[1] = (short)f2bf(at1);
      af[2] = (short)f2bf(at2); af[3] = (short)f2bf(at3);
      af[4] = (short)f2bf(at4); af[5] = (short)f2bf(at5);
      af[6] = (short)f2bf(at6); af[7] = (short)f2bf(at7);
      const int o = w*2 + ol;
      #pragma unroll
      for (int dt = 0; dt < 6; ++dt) {
        const unsigned short* vp = vht + ((size_t)(b*8+o)*96 + dt*16 + ci)*NP_ + m0 + g*8;
        bf16x8 bf = *(const bf16x8*)(vp);
        xq[ol][dt] = mfma16(af, bf, xq[ol][dt]);
      }
    }
    __syncthreads();
  }
  #pragma unroll
  for (int ol = 0; ol < 2; ++ol) {
    const int o = w*2 + ol;
    #pragma unroll
    for (int dt = 0; dt < 6; ++dt)
      #pragma unroll
      for (int r = 0; r < 4; ++r)
        xout[((size_t)b*N_ + rt*16 + g*4 + r)*C_ + o*96 + dt*16 + ci] = f2bf(xq[ol][dt][r]);
  }
}

// ---------------- K5: output projection x @ Wp^T + bp (fp32 out) ----------------
__global__ __launch_bounds__(256) void k_proj(const unsigned short* __restrict__ x,
    const unsigned short* __restrict__ wpb, const float* __restrict__ bp, float* __restrict__ out)
{
  const int rb = blockIdx.x, cb = blockIdx.y;
  const int tid = threadIdx.x, w = tid >> 6, lane = tid & 63, g = lane >> 4, ci = lane & 15;
  const int row0 = rb*64 + w*16;
  const int col0 = cb*64;
  f32x4 acc[4];
  #pragma unroll
  for (int ct = 0; ct < 4; ++ct) acc[ct] = (f32x4){0.f, 0.f, 0.f, 0.f};
  for (int k0 = 0; k0 < 768; k0 += 32) {
    bf16x8 a = *(const bf16x8*)(x + (size_t)(row0+ci)*768 + k0 + g*8);
    #pragma unroll
    for (int ct = 0; ct < 4; ++ct) {
      bf16x8 bb = *(const bf16x8*)(wpb + (size_t)(col0+ct*16+ci)*768 + k0 + g*8);
      acc[ct] = mfma16(a, bb, acc[ct]);
    }
  }
  #pragma unroll
  for (int ct = 0; ct < 4; ++ct) {
    const int c = col0 + ct*16 + ci;
    const float bias = bp[c];
    #pragma unroll
    for (int r = 0; r < 4; ++r)
      out[(size_t)(row0 + g*4 + r)*768 + c] = acc[ct][r] + bias;
  }
}

extern "C" void kernel_launch(void* const* d_in, const int* in_sizes, int n_in,
                              void* d_out, int out_size, void* d_ws, size_t ws_size,
                              hipStream_t stream) {
  const float* q     = (const float*)d_in[0];
  const float* k     = (const float*)d_in[1];
  const float* v     = (const float*)d_in[2];
  const float* Wq    = (const float*)d_in[3];
  const float* Wk    = (const float*)d_in[4];
  const float* Wv    = (const float*)d_in[5];
  const float* Wre   = (const float*)d_in[6];
  const float* bre   = (const float*)d_in[7];
  const float* gamma = (const float*)d_in[8];
  const float* beta  = (const float*)d_in[9];
  const float* Wp    = (const float*)d_in[10];
  const float* bp    = (const float*)d_in[11];
  char* ws = (char*)d_ws;
  unsigned short* qh  = (unsigned short*)(ws + OFF_QH);
  unsigned short* kh  = (unsigned short*)(ws + OFF_KH);
  unsigned short* vht = (unsigned short*)(ws + OFF_VHT);
  float* Zb   = (float*)(ws + OFF_Z);
  float* G    = (float*)(ws + OFF_G);
  float* coef = (float*)(ws + OFF_COEF);
  unsigned short* xb  = (unsigned short*)(ws + OFF_X);
  unsigned short* wpb = (unsigned short*)(ws + OFF_WPB);

  hipMemsetAsync(ws + OFF_G, 0, SZ_G, stream);
  hipMemsetAsync(ws + OFF_VHT, 0, SZ_VHT, stream);   // zero m-padding for PV tail chunk

  k_conv<<<dim3(B_*N_, 3), 256, 0, stream>>>(q, k, v, Wq, Wk, Wv, qh, kh, vht);
  k_cast<<<dim3(576), 256, 0, stream>>>(Wp, wpb);
  k_zsum<<<dim3(NT, B_), 256, 0, stream>>>(qh, kh, Zb);
  k_gstat<<<dim3(NT, B_), 256, 0, stream>>>(qh, kh, Zb, G);
  k_coef<<<dim3(1), 64, 0, stream>>>(G, Wre, bre, gamma, beta, coef);
  k_attn<<<dim3(NT, B_), 256, 0, stream>>>(qh, kh, vht, Zb, coef, xb);
  k_proj<<<dim3(98, 12), 256, 0, stream>>>(xb, wpb, bp, (float*)d_out);
}